// Round 8
// baseline (121.856 us; speedup 1.0000x reference)
//
#include <hip/hip_runtime.h>
#include <hip/hip_bf16.h>
#include <math.h>

#define B_N 8192
#define D_K 256
#define TILE 128
#define NT 512              // 8 waves, 2x4 wave grid, 64x32 per wave (r0/r7-proven, ~52 VGPR)
#define NBLK 64             // B_N / TILE
#define NPAIR 2080          // NBLK*(NBLK+1)/2 upper-triangular tile pairs
#define NCLS 100
#define KEXP 28.8539008177792681f   // 20*log2(e): e^(sim-20) = 2^((dot-1)*KEXP)
#define KCH 32              // K elements per chunk: 8 chunks, 4-buffer counted-vmcnt pipeline
#define NCHUNK 8
#define GRID_MAIN 512       // persistent: 2 blocks/CU; block b owns tiles b, b+512, ...

typedef __attribute__((ext_vector_type(8))) short short8;
typedef __attribute__((ext_vector_type(4))) float f32x4;

template <bool V> struct BoolC { static constexpr bool value = V; };

__device__ __forceinline__ unsigned short f2bf(float x) {
    unsigned int u = __float_as_uint(x);
    unsigned int r = (u + 0x7FFFu + ((u >> 16) & 1u)) >> 16;
    return (unsigned short)r;
}

// async global->LDS, 16B per lane: dest = (wave-uniform) lds base + lane*16
__device__ __forceinline__ void gload_lds16(const short* g, short* l) {
    __builtin_amdgcn_global_load_lds(
        (const __attribute__((address_space(1))) void*)g,
        (__attribute__((address_space(3))) void*)l, 16, 0, 0);
}

// sum over each aligned 16-lane group on the VALU pipe (DPP butterfly+mirrors).
__device__ __forceinline__ float row_sum16(float v) {
    v += __int_as_float(__builtin_amdgcn_update_dpp(0, __float_as_int(v), 0xB1, 0xF, 0xF, true));
    v += __int_as_float(__builtin_amdgcn_update_dpp(0, __float_as_int(v), 0x4E, 0xF, 0xF, true));
    v += __int_as_float(__builtin_amdgcn_update_dpp(0, __float_as_int(v), 0x141, 0xF, 0xF, true));
    v += __int_as_float(__builtin_amdgcn_update_dpp(0, __float_as_int(v), 0x140, 0xF, 0xF, true));
    return v;
}

// tile index -> (a,b) upper-triangular pair
__device__ __forceinline__ void decode_pair(int t, int& a, int& b) {
    int bb = (int)((sqrtf(8.0f * t + 1.0f) - 1.0f) * 0.5f);
    while ((bb + 1) * (bb + 2) / 2 <= t) ++bb;
    while (bb * (bb + 1) / 2 > t) --bb;
    a = t - bb * (bb + 1) / 2;
    b = bb;
}

// -------- Kernel 1: normalize rows -> bf16; block 0 also: label hist + zero accums --------
__global__ void prep_kernel(const float* __restrict__ feat, unsigned short* __restrict__ fnorm,
                            const int* __restrict__ labels, int* __restrict__ cnt,
                            float* __restrict__ gscal, double* __restrict__ accum,
                            unsigned int* __restrict__ done) {
    if (blockIdx.x == 0) {
        __shared__ int h[NCLS];
        int t = threadIdx.x;
        if (t < NCLS) h[t] = 0;
        if (t == 0) {
            gscal[0] = 0.f; gscal[1] = 0.f;
            accum[0] = 0.0; accum[1] = 0.0; accum[2] = 0.0;
            *done = 0u;
        }
        __syncthreads();
        for (int r = t; r < B_N; r += 256) atomicAdd(&h[labels[r]], 1);
        __syncthreads();
        if (t < NCLS) cnt[t] = h[t];
    }
    int wave = threadIdx.x >> 6, lane = threadIdx.x & 63;
    int row = blockIdx.x * 4 + wave;
    float4 v = *(const float4*)(feat + (size_t)row * D_K + lane * 4);
    float ss = v.x * v.x + v.y * v.y + v.z * v.z + v.w * v.w;
    #pragma unroll
    for (int off = 1; off < 64; off <<= 1) ss += __shfl_xor(ss, off);
    float inv = 1.0f / fmaxf(sqrtf(ss), 1e-12f);
    ushort4 o;
    o.x = f2bf(v.x * inv); o.y = f2bf(v.y * inv);
    o.z = f2bf(v.z * inv); o.w = f2bf(v.w * inv);
    *(ushort4*)(fnorm + (size_t)row * D_K + lane * 4) = o;
}

// -------- Kernel 2: PERSISTENT counted-vmcnt pipeline, wrap-around across tiles --------
// r0-r7 established: the 50us floor is invariant to waves/CU, LDS volume, and drain
// semantics; the remaining exposed cost is per-tile setup (launch, label load, cold DMA
// of chunks 0-2 with nothing to hide the latency) paid 2080 times, plus end-of-grid drain.
// Persistence with STATIC tile assignment (block b: tiles b, b+512, ...) removes it:
//   every slot is uniformly  WAITV(4); BARX; COMPUTE(kc); ISSUE(kc+3)
// where slots 5-7 "ISSUE" the NEXT tile's chunks 0-2 (wrap-around). Invariants:
//  - landing: before COMPUTE(kc), outstanding = chunks kc,kc+1,kc+2 (6 loads) ->
//    WAITV(4) retires chunk kc for this wave; BARX certifies it for all waves.
//    (Epilogue stores also count in vmcnt -> slot-0 over-waits slightly; still correct.)
//  - overwrite: ISSUE(kc+3) targets buf[(kc-1)&3], last read at COMPUTE(kc-1), certified
//    by the BARX before COMPUTE(kc).
// Diag tiles stage B too (same addresses, identical data) so every tile runs the same
// schedule. Epilogue barriers are raw lgkmcnt(0)+s_barrier: __syncthreads would emit
// vmcnt(0) and drain the next tile's in-flight chunks. Last tile issues clamped dummy
// chunks (keeps WAITV immediates valid); WAITV(0) before exit drains them.
// ghs reset moved behind a second barrier (fixes r3's latent read/reset race).
#define WAITV(N) asm volatile("s_waitcnt vmcnt(" #N ")" ::: "memory")
#define BARX() __builtin_amdgcn_s_barrier()
#define LGKB() { asm volatile("s_waitcnt lgkmcnt(0)" ::: "memory"); __builtin_amdgcn_s_barrier(); }

__global__ __launch_bounds__(NT, 4) void main_kernel(
        const unsigned short* __restrict__ fnorm, const int* __restrict__ labels,
        float2* __restrict__ G, float* __restrict__ gscal) {
    __shared__ short As[4][TILE * KCH];         // 4 x 8 KB
    __shared__ short Bs[4][TILE * KCH];         // 4 x 8 KB
    __shared__ int Ls[2 * TILE];
    __shared__ float2 Rbuf[4 * TILE];           // [wn 0..3][128] row partials
    __shared__ float2 Cbuf[2 * TILE];           // [wm 0..1][128] col partials
    __shared__ int ghs[8];
    __shared__ float gps[8];

    const int tid = threadIdx.x;
    const int lane = tid & 63, wave = tid >> 6;
    const int wm = wave >> 2, wn = wave & 3;    // 2 (row) x 4 (col) waves; each 64x32
    const int l15 = lane & 15, lhi = lane >> 4;
    const short* fn = (const short*)fnorm;

    // staging (chunk = 128 rows x 64B = 8KB = 512 threads x 16B): thread t stages phys
    // slot t&3 of row t>>2 holding global sub-chunk (t&3)^((t>>3)&3); LDS dest linear.
    const int rs = tid >> 2, cs = (tid & 3) ^ ((tid >> 3) & 3);
    const int uds = (tid & ~63) * 8;            // shorts; wave-uniform base, HW adds lane*16B
    const int stg = rs * D_K + cs * 8;

    // fragment LDS offsets (tile/chunk-invariant): read slot = lhi ^ ((l15>>1)&3)
    const int ch8 = (lhi ^ ((l15 >> 1) & 3)) * 8;
    int aoff[4], boff[2];
    #pragma unroll
    for (int mi = 0; mi < 4; mi++) aoff[mi] = (wm * 64 + mi * 16 + l15) * KCH + ch8;
    #pragma unroll
    for (int ni = 0; ni < 2; ni++) boff[ni] = (wn * 32 + ni * 16 + l15) * KCH + ch8;

    int t = blockIdx.x, a, b;
    decode_pair(t, a, b);
    int row0 = a * TILE, col0 = b * TILE;
    bool diag = (a == b);
    int abase = row0 * D_K + stg;               // 32-bit offsets: fnorm is 4MB
    int bbase = col0 * D_K + stg;

    if (tid < 128) Ls[tid] = labels[row0 + tid];
    else if (tid < 256) Ls[tid] = labels[col0 + tid - 128];
    if (lane == 0) ghs[wave] = 0;

#define ISSUE(kc)  { gload_lds16(fn + abase + (kc) * KCH, &As[(kc) & 3][uds]); \
                     gload_lds16(fn + bbase + (kc) * KCH, &Bs[(kc) & 3][uds]); }
#define ISSUE_N(c) { gload_lds16(fn + nabase + (c) * KCH, &As[(c) & 3][uds]); \
                     gload_lds16(fn + nbbase + (c) * KCH, &Bs[(c) & 3][uds]); }
#define COMPUTE(kc) { \
    const short* Ap = As[(kc) & 3]; \
    const short* Bp = Bs[(kc) & 3]; \
    short8 af[4], bfr[2]; \
    _Pragma("unroll") for (int mi = 0; mi < 4; mi++) af[mi] = *(const short8*)&Ap[aoff[mi]]; \
    _Pragma("unroll") for (int ni = 0; ni < 2; ni++) bfr[ni] = *(const short8*)&Bp[boff[ni]]; \
    __builtin_amdgcn_s_setprio(1); \
    _Pragma("unroll") for (int mi = 0; mi < 4; mi++) \
        _Pragma("unroll") for (int ni = 0; ni < 2; ni++) \
            acc[mi][ni] = __builtin_amdgcn_mfma_f32_16x16x32_bf16(af[mi], bfr[ni], acc[mi][ni], 0, 0, 0); \
    __builtin_amdgcn_s_setprio(0); }

    // prologue: first tile's chunks 0-2 in flight
    ISSUE(0) ISSUE(1) ISSUE(2)

    for (;;) {
        f32x4 acc[4][2];
        #pragma unroll
        for (int i = 0; i < 4; i++)
            #pragma unroll
            for (int j = 0; j < 2; j++) acc[i][j] = {0.f, 0.f, 0.f, 0.f};

        WAITV(4); BARX(); COMPUTE(0) ISSUE(3)
        WAITV(4); BARX(); COMPUTE(1) ISSUE(4)
        WAITV(4); BARX(); COMPUTE(2) ISSUE(5)
        WAITV(4); BARX(); COMPUTE(3) ISSUE(6)
        WAITV(4); BARX(); COMPUTE(4) ISSUE(7)
        // next-tile decode (hidden under MFMA phases); clamp so the last tile issues
        // valid dummy addresses, keeping all WAITV immediates correct
        const int nt = t + GRID_MAIN;
        int na, nb2;
        decode_pair(nt < NPAIR ? nt : 0, na, nb2);
        const int nrow0 = na * TILE, ncol0 = nb2 * TILE;
        const int nabase = nrow0 * D_K + stg, nbbase = ncol0 * D_K + stg;
        WAITV(4); BARX(); COMPUTE(5) ISSUE_N(0)
        WAITV(4); BARX(); COMPUTE(6) ISSUE_N(1)
        WAITV(4); BARX(); COMPUTE(7) ISSUE_N(2)

        // ---- Epilogue (r0-verified, bit-exact). C/D: col = lane&15, row = (lane>>4)*4+reg
        int lc[2], colg[2];
        #pragma unroll
        for (int ni = 0; ni < 2; ni++) {
            int c = wn * 32 + ni * 16 + l15;
            lc[ni] = Ls[128 + c];
            colg[ni] = col0 + c;
        }

        auto body = [&](auto DIAGC) {
            constexpr bool DIAG = decltype(DIAGC)::value;
            float cD[2] = {0.f, 0.f};
            float gp = 0.f;           // sum of positive-pair dots (this tile)
            bool anyhi = false;       // lane-mask predicate (SALU)

            #pragma unroll
            for (int mi = 0; mi < 4; mi++) {
                #pragma unroll
                for (int reg = 0; reg < 4; reg++) {
                    int rloc = wm * 64 + mi * 16 + lhi * 4 + reg;
                    int rowg = row0 + rloc;
                    int lr = Ls[rloc];
                    float d = 0.f;
                    #pragma unroll
                    for (int ni = 0; ni < 2; ni++) {
                        float dot = acc[mi][ni][reg];
                        float e = __builtin_exp2f((dot - 1.0f) * KEXP);   // e^(sim-20)
                        bool ns = !DIAG || (rowg != colg[ni]);   // off-diag: folds to true
                        float ev = ns ? e : 0.f;
                        d += ev; cD[ni] += ev;
                        bool ps = ns && (lr == lc[ni]);
                        gp += ps ? dot : 0.f;
                        anyhi = anyhi | (ps & (dot > 0.7f));
                    }
                    d = row_sum16(d);                  // VALU pipe, not LDS pipe
                    if (l15 == 0) Rbuf[wn * 128 + rloc] = {d, 0.f};
                }
            }

            if (!DIAG) {
                #pragma unroll
                for (int ni = 0; ni < 2; ni++) {
                    cD[ni] += __shfl_xor(cD[ni], 16);
                    cD[ni] += __shfl_xor(cD[ni], 32);
                }
                if (lhi == 0) {
                    #pragma unroll
                    for (int ni = 0; ni < 2; ni++)
                        Cbuf[wm * 128 + wn * 32 + ni * 16 + l15] = {cD[ni], 0.f};
                }
            }

            gp = row_sum16(gp);
            gp += __shfl_xor(gp, 16);
            gp += __shfl_xor(gp, 32);
            if (lane == 0) gps[wave] = gp;

            // ---- Rare path: any high-similarity positive in this wave ----
            if (__any(anyhi)) {
                float cR[2] = {0.f, 0.f};
                int nhi = 0;
                #pragma unroll
                for (int mi = 0; mi < 4; mi++) {
                    #pragma unroll
                    for (int reg = 0; reg < 4; reg++) {
                        int rloc = wm * 64 + mi * 16 + lhi * 4 + reg;
                        int rowg = row0 + rloc;
                        int lr = Ls[rloc];
                        float rx = 0.f;
                        #pragma unroll
                        for (int ni = 0; ni < 2; ni++) {
                            float dot = acc[mi][ni][reg];
                            bool ns = !DIAG || (rowg != colg[ni]);
                            bool hi = ns && (lr == lc[ni]) && (dot > 0.7f);
                            float e = hi ? __builtin_exp2f((dot - 1.0f) * KEXP) : 0.f;
                            rx += e; cR[ni] += e; nhi += hi ? 1 : 0;
                        }
                        rx = row_sum16(rx);
                        if (l15 == 0) Rbuf[wn * 128 + rloc].y = rx;
                    }
                }
                if (!DIAG) {
                    #pragma unroll
                    for (int ni = 0; ni < 2; ni++) {
                        cR[ni] += __shfl_xor(cR[ni], 16);
                        cR[ni] += __shfl_xor(cR[ni], 32);
                    }
                    if (lhi == 0) {
                        #pragma unroll
                        for (int ni = 0; ni < 2; ni++)
                            Cbuf[wm * 128 + wn * 32 + ni * 16 + l15].y = cR[ni];
                    }
                }
                #pragma unroll
                for (int off = 1; off < 64; off <<= 1) nhi += __shfl_xor(nhi, off);
                if (lane == 0) ghs[wave] = nhi;
            }
        };
        if (diag) body(BoolC<true>{});
        else body(BoolC<false>{});

        LGKB();   // sync1: all Rbuf/Cbuf/gps/ghs writes complete+visible (no vmcnt drain!)

        if (tid < 128) {
            int r = tid;
            float2 a0 = Rbuf[r], a1 = Rbuf[128 + r], a2 = Rbuf[256 + r], a3 = Rbuf[384 + r];
            G[(size_t)b * B_N + row0 + r] = {a0.x + a1.x + a2.x + a3.x, a0.y + a1.y + a2.y + a3.y};
        } else if (tid < 256 && !diag) {
            int c = tid - 128;
            float2 a0 = Cbuf[c], a1 = Cbuf[128 + c];
            G[(size_t)a * B_N + col0 + c] = {a0.x + a1.x, a0.y + a1.y};
        }
        if (tid == 0) {
            float w = diag ? 1.0f : 2.0f;   // off-diag tile stands for (i,j) and (j,i)
            float gpt = gps[0] + gps[1] + gps[2] + gps[3] + gps[4] + gps[5] + gps[6] + gps[7];
            atomicAdd(&gscal[0], w * gpt);
            int tot = ghs[0] + ghs[1] + ghs[2] + ghs[3] + ghs[4] + ghs[5] + ghs[6] + ghs[7];
            if (tot > 0) atomicAdd(&gscal[1], w * (float)tot);
        }

        LGKB();   // sync2: tid0's ghs/gps reads done before next tile's resets/Ls writes

        if (nt >= NPAIR) break;
        t = nt; a = na; b = nb2; row0 = nrow0; col0 = ncol0; diag = (na == nb2);
        abase = nabase; bbase = nbbase;
        if (tid < 128) Ls[tid] = labels[row0 + tid];
        else if (tid < 256) Ls[tid] = labels[col0 + tid - 128];
        if (lane == 0) ghs[wave] = 0;
    }
    WAITV(0);   // drain dummy last-tile DMAs before LDS dealloc at exit
}

// -------- Kernel 3: per-row reduction over 64 slots + last-block final assembly --------
__global__ void finalize_kernel(const float2* __restrict__ G, const int* __restrict__ labels,
                                const int* __restrict__ cnt, const float* __restrict__ gscal,
                                double* __restrict__ accum, unsigned int* __restrict__ done,
                                float* __restrict__ out) {
    int lane = threadIdx.x & 63, q = threadIdx.x >> 6;   // q = slot quarter
    int r = blockIdx.x * 64 + lane;
    float d = 0.f, rx = 0.f;
    #pragma unroll
    for (int s = 0; s < 16; ++s) {
        float2 g = G[(size_t)(q * 16 + s) * B_N + r];
        d += g.x; rx += g.y;
    }
    __shared__ float2 sh[4][64];
    sh[q][lane] = {d, rx};
    __syncthreads();
    if (threadIdx.x < 64) {
        int rr = blockIdx.x * 64 + threadIdx.x;
        float2 t0 = sh[0][threadIdx.x], t1 = sh[1][threadIdx.x];
        float2 t2 = sh[2][threadIdx.x], t3 = sh[3][threadIdx.x];
        float dd = t0.x + t1.x + t2.x + t3.x;
        float rr2 = t0.y + t1.y + t2.y + t3.y;
        float np = (float)(cnt[labels[rr]] - 1);
        float ld = logf(dd + 1e-12f) + 20.0f;             // log_denom (shift 20)
        double s1 = (double)np * (double)ld;
        double s2 = (double)np;
        double s3 = (rr2 > 0.f) ? (double)logf(rr2 + 1.0f) : 0.0;  // baseline=0: sim_max=20
        #pragma unroll
        for (int off = 1; off < 64; off <<= 1) {
            s1 += __shfl_xor(s1, off);
            s2 += __shfl_xor(s2, off);
            s3 += __shfl_xor(s3, off);
        }
        if (threadIdx.x == 0) {
            atomicAdd(&accum[0], s1);
            atomicAdd(&accum[1], s2);
            atomicAdd(&accum[2], s3);
            __threadfence();
            unsigned int tk = atomicAdd(done, 1u);
            if (tk == gridDim.x - 1) {           // last block assembles the scalar
                double a1 = atomicAdd(&accum[0], 0.0);
                double a2 = atomicAdd(&accum[1], 0.0);
                double a3 = atomicAdd(&accum[2], 0.0);
                double gp = (double)gscal[0];    // sum over ordered pos pairs of dot
                double gh = (double)gscal[1];    // count of high ordered pairs
                double scl = (a2 > 0.0) ? (a1 - 20.0 * gp) / fmax(a2, 1.0) : 0.0;
                double rel = (gh > 0.0) ? a3 / fmax(gh, 1.0) : 0.0;
                double tot = scl + rel;          // BETA = 1.0
                tot = fmin(fmax(tot, 0.0), 10.0);
                out[0] = (float)tot;
            }
        }
    }
}

extern "C" void kernel_launch(void* const* d_in, const int* in_sizes, int n_in,
                              void* d_out, int out_size, void* d_ws, size_t ws_size,
                              hipStream_t stream) {
    const float* feat = (const float*)d_in[0];
    const int* labels = (const int*)d_in[1];
    float* out = (float*)d_out;
    char* ws = (char*)d_ws;

    unsigned short* fnorm = (unsigned short*)(ws);                          // 4 MB
    float2* G          = (float2*)(ws + (size_t)4 * 1024 * 1024);           // 4 MB: [64][8192]
    int*    cnt        = (int*)(ws + (size_t)8 * 1024 * 1024);              // 400 B
    float*  gscal      = (float*)(ws + (size_t)8 * 1024 * 1024 + 1024);     // 8 B
    double* accum      = (double*)(ws + (size_t)8 * 1024 * 1024 + 2048);    // 24 B
    unsigned int* done = (unsigned int*)(ws + (size_t)8 * 1024 * 1024 + 3072); // 4 B

    prep_kernel<<<B_N / 4, 256, 0, stream>>>(feat, fnorm, labels, cnt, gscal, accum, done);
    main_kernel<<<GRID_MAIN, NT, 0, stream>>>(fnorm, labels, G, gscal);
    finalize_kernel<<<B_N / 64, 256, 0, stream>>>(G, labels, cnt, gscal, accum, done, out);
    (void)in_sizes; (void)n_in; (void)out_size; (void)ws_size;
}